// Round 2
// baseline (77.763 us; speedup 1.0000x reference)
//
#include <hip/hip_runtime.h>

// QConv2D quanvolution, Heisenberg-picture restructure.
// z_w(patch) = Tr(rho(angles) * U^dag Z_w U) with U fixed by params.
// rho is a product state with per-wire Bloch vector (0, -sin a, cos a), so
//   z_w = sum_{P in {I,Y,Z}^4} c_{w,P} * prod_q t_q(P_q),
//   t(I)=1, t(Y)=-sin a_q, t(Z)=cos a_q.
// setup_kernel (1 block): builds U columns in LDS, then 324 threads compute
// the 4x81 coefficient table into d_ws. Main kernel: 4 sincos + nested
// 3x3x3x3 contraction (~320 fma) per patch — ~4x fewer inst than direct sim.
// Wire q <-> state bit (8>>q).

#define HH 128
#define WW 128
#define HO 127
#define WO 127
#define BB 32

template <int M>
__device__ __forceinline__ void rx_gate(float* re, float* im, float th) {
    float s, c;
    __sincosf(th * 0.5f, &s, &c);
#pragma unroll
    for (int idx = 0; idx < 16; ++idx) {
        if (idx & M) continue;
        const int p = idx | M;
        float r0 = re[idx], i0 = im[idx], r1 = re[p], i1 = im[p];
        re[idx] = fmaf(c, r0, s * i1);
        im[idx] = fmaf(c, i0, -s * r1);
        re[p]   = fmaf(c, r1, s * i0);
        im[p]   = fmaf(c, i1, -s * r0);
    }
}

template <int M>
__device__ __forceinline__ void rz_gate(float* re, float* im, float th) {
    float sp, cp;
    __sincosf(th * 0.5f, &sp, &cp);
#pragma unroll
    for (int idx = 0; idx < 16; ++idx) {
        float r = re[idx], q = im[idx];
        if (idx & M) {
            re[idx] = fmaf(r, cp, -q * sp);
            im[idx] = fmaf(q, cp, r * sp);
        } else {
            re[idx] = fmaf(r, cp, q * sp);
            im[idx] = fmaf(q, cp, -r * sp);
        }
    }
}

template <int CM, int TM>
__device__ __forceinline__ void cnot_gate(float* re, float* im) {
#pragma unroll
    for (int idx = 0; idx < 16; ++idx) {
        if ((idx & CM) && !(idx & TM)) {
            const int p = idx | TM;
            float t;
            t = re[idx]; re[idx] = re[p]; re[p] = t;
            t = im[idx]; im[idx] = im[p]; im[p] = t;
        }
    }
}

__device__ __forceinline__ void param_circuit(float* re, float* im,
                                              const float* __restrict__ prm) {
#pragma unroll
    for (int l = 0; l < 2; ++l) {
        const float* p = prm + l * 8;
        rx_gate<8>(re, im, p[0]); rz_gate<8>(re, im, p[1]);
        rx_gate<4>(re, im, p[2]); rz_gate<4>(re, im, p[3]);
        rx_gate<2>(re, im, p[4]); rz_gate<2>(re, im, p[5]);
        rx_gate<1>(re, im, p[6]); rz_gate<1>(re, im, p[7]);
        cnot_gate<4, 8>(re, im);
        cnot_gate<2, 4>(re, im);
        cnot_gate<1, 2>(re, im);
    }
}

// One block. Phase A: 16 threads simulate U|j> -> LDS. Phase B: 324 threads
// compute W[w*81 + p] = Tr((tensor P) U^dag Z_w U)/16, p base-3 (p3 least
// significant), digit 0=I,1=Y,2=Z on wire q.
__global__ __launch_bounds__(384) void qconv_setup(const float* __restrict__ prm,
                                                   float* __restrict__ W) {
    __shared__ float Ur[16][16];  // [row k][col j]
    __shared__ float Ui[16][16];
    const int tid = threadIdx.x;
    if (tid < 16) {
        float re[16], im[16];
#pragma unroll
        for (int k = 0; k < 16; ++k) { re[k] = (k == tid) ? 1.f : 0.f; im[k] = 0.f; }
        param_circuit(re, im, prm);
#pragma unroll
        for (int k = 0; k < 16; ++k) { Ur[k][tid] = re[k]; Ui[k][tid] = im[k]; }
    }
    __syncthreads();
    if (tid < 324) {
        const int w = tid / 81;
        int p = tid % 81;
        const int t3 = p % 3; p /= 3;
        const int t2 = p % 3; p /= 3;
        const int t1 = p % 3;
        const int t0 = p / 3;
        // Y (type 1) is the only off-diagonal Pauli here -> flip mask
        const int f = (t0 == 1 ? 8 : 0) | (t1 == 1 ? 4 : 0) |
                      (t2 == 1 ? 2 : 0) | (t3 == 1 ? 1 : 0);
        const int zbit = 8 >> w;
        float acc = 0.f;
        for (int i = 0; i < 16; ++i) {
            // phase = P[i][i^f] over the 4 wires; entries in {1,-1,i,-i}
            float pr = 1.f, pi = 0.f;
            {
                // Z: diag(1,-1). Y: Y[0][1]=-i, Y[1][0]=+i.
                int ib;
                ib = (i >> 3) & 1;
                if (t0 == 2) { if (ib) { pr = -pr; pi = -pi; } }
                else if (t0 == 1) { float tt = pr; if (ib) { pr = -pi; pi = tt; } else { pr = pi; pi = -tt; } }
                ib = (i >> 2) & 1;
                if (t1 == 2) { if (ib) { pr = -pr; pi = -pi; } }
                else if (t1 == 1) { float tt = pr; if (ib) { pr = -pi; pi = tt; } else { pr = pi; pi = -tt; } }
                ib = (i >> 1) & 1;
                if (t2 == 2) { if (ib) { pr = -pr; pi = -pi; } }
                else if (t2 == 1) { float tt = pr; if (ib) { pr = -pi; pi = tt; } else { pr = pi; pi = -tt; } }
                ib = i & 1;
                if (t3 == 2) { if (ib) { pr = -pr; pi = -pi; } }
                else if (t3 == 1) { float tt = pr; if (ib) { pr = -pi; pi = tt; } else { pr = pi; pi = -tt; } }
            }
            const int j = i ^ f;
            // M[j][i] = sum_k conj(U[k][j]) z_k U[k][i]
            float sr = 0.f, si = 0.f;
            for (int k = 0; k < 16; ++k) {
                float zk = (k & zbit) ? -1.f : 1.f;
                float ar = Ur[k][j], ai = Ui[k][j];
                float br = Ur[k][i], bi = Ui[k][i];
                sr += zk * fmaf(ar, br, ai * bi);
                si += zk * fmaf(ar, bi, -ai * br);
            }
            acc += pr * sr - pi * si;
        }
        W[tid] = acc * (1.0f / 16.0f);
    }
}

__global__ __launch_bounds__(256) void qconv_eval(
    const float* __restrict__ x, const float* __restrict__ W,
    float* __restrict__ out, int total) {
    int tid = blockIdx.x * blockDim.x + threadIdx.x;
    if (tid >= total) return;

    int j = tid % WO;
    int t = tid / WO;
    int i = t % HO;
    int b = t / HO;

    const float* xp = x + ((size_t)b * HH + i) * WW + j;
    float a0 = xp[0], a1 = xp[1], a2 = xp[WW], a3 = xp[WW + 1];

    // t(Y) = -sin(a), t(Z) = cos(a) — full angle
    float s0, c0, s1, c1, s2, c2, s3, c3;
    __sincosf(a0, &s0, &c0);
    __sincosf(a1, &s1, &c1);
    __sincosf(a2, &s2, &c2);
    __sincosf(a3, &s3, &c3);
    const float y0 = -s0, y1 = -s1, y2 = -s2, y3 = -s3;

    float z[4];
#pragma unroll
    for (int w = 0; w < 4; ++w) {
        const float* Ww = W + w * 81;
        float accw = 0.f;
#pragma unroll
        for (int p0 = 0; p0 < 3; ++p0) {
            float b0 = 0.f;
#pragma unroll
            for (int p1 = 0; p1 < 3; ++p1) {
                float b1 = 0.f;
#pragma unroll
                for (int p2 = 0; p2 < 3; ++p2) {
                    const float* q = Ww + ((p0 * 3 + p1) * 3 + p2) * 3;
                    float d = fmaf(c3, q[2], fmaf(y3, q[1], q[0]));
                    if (p2 == 0)      b1 += d;
                    else if (p2 == 1) b1 = fmaf(y2, d, b1);
                    else              b1 = fmaf(c2, d, b1);
                }
                if (p1 == 0)      b0 += b1;
                else if (p1 == 1) b0 = fmaf(y1, b1, b0);
                else              b0 = fmaf(c1, b1, b0);
            }
            if (p0 == 0)      accw += b0;
            else if (p0 == 1) accw = fmaf(y0, b0, accw);
            else              accw = fmaf(c0, b0, accw);
        }
        z[w] = accw;
    }

    float* o = out + (((size_t)b * 4) * HO + (size_t)i) * WO + j;
    o[0]           = z[0];
    o[HO * WO]     = z[1];
    o[2 * HO * WO] = z[2];
    o[3 * HO * WO] = z[3];
}

extern "C" void kernel_launch(void* const* d_in, const int* in_sizes, int n_in,
                              void* d_out, int out_size, void* d_ws, size_t ws_size,
                              hipStream_t stream) {
    const float* x = (const float*)d_in[0];
    const float* prm = (const float*)d_in[1];
    float* out = (float*)d_out;
    float* W = (float*)d_ws;  // 324 floats

    qconv_setup<<<1, 384, 0, stream>>>(prm, W);

    const int total = BB * HO * WO;  // 516128 patches
    const int blocks = (total + 255) / 256;
    qconv_eval<<<blocks, 256, 0, stream>>>(x, W, out, total);
}